// Round 1
// baseline (4483.373 us; speedup 1.0000x reference)
//
#include <hip/hip_runtime.h>
#include <math.h>

#define S_LEN 2048
#define HID   1024
#define NH    16
#define HD    64
#define BATCH 2

// ---------------- GEMM: C = A @ W^T ----------------
// A: (M,K) row-major, W: (N,K) row-major.
// MODE 0: plain write C[m*N+n]                      (output projection)
// MODE 1: RoPE + transposed write to (B,NH,S,HD)    (Q, K)
// MODE 2: transposed write to (B,NH,S,HD)           (V)
template <int MODE>
__global__ __launch_bounds__(256) void gemm_xwT(
    const float* __restrict__ A, const float* __restrict__ W,
    float* __restrict__ C, int M, int N, int K)
{
    __shared__ float As[16][65];
    __shared__ float Bs[16][65];
    const int tid = threadIdx.x;
    const int tx = tid & 15, ty = tid >> 4;
    const int m0 = blockIdx.x * 64, n0 = blockIdx.y * 64;

    float acc[4][4] = {};

    for (int k0 = 0; k0 < K; k0 += 16) {
        #pragma unroll
        for (int l = 0; l < 4; ++l) {
            int e = tid + l * 256;
            int r = e >> 4, c = e & 15;
            As[c][r] = A[(size_t)(m0 + r) * K + k0 + c];
            Bs[c][r] = W[(size_t)(n0 + r) * K + k0 + c];
        }
        __syncthreads();
        #pragma unroll
        for (int kk = 0; kk < 16; ++kk) {
            float a[4], b[4];
            #pragma unroll
            for (int i = 0; i < 4; ++i) a[i] = As[kk][ty + 16 * i];
            #pragma unroll
            for (int j = 0; j < 4; ++j) b[j] = Bs[kk][tx + 16 * j];
            #pragma unroll
            for (int i = 0; i < 4; ++i)
                #pragma unroll
                for (int j = 0; j < 4; ++j)
                    acc[i][j] += a[i] * b[j];
        }
        __syncthreads();
    }

    if (MODE == 0) {
        #pragma unroll
        for (int i = 0; i < 4; ++i) {
            int m = m0 + ty + 16 * i;
            #pragma unroll
            for (int j = 0; j < 4; ++j) {
                int n = n0 + tx + 16 * j;
                C[(size_t)m * N + n] = acc[i][j];
            }
        }
    } else {
        const int h = n0 >> 6;  // n0 is a multiple of 64, tile spans one head
        #pragma unroll
        for (int i = 0; i < 4; ++i) {
            int m  = m0 + ty + 16 * i;
            int b  = m >> 11;          // / S_LEN
            int sp = m & (S_LEN - 1);  // % S_LEN
            size_t base = (((size_t)b * NH + h) * S_LEN + sp) * HD;
            if (MODE == 2) {
                #pragma unroll
                for (int j = 0; j < 4; ++j) {
                    int d = tx + 16 * j;
                    C[base + d] = acc[i][j];
                }
            } else {  // MODE 1: RoPE. pair (d1, d1+32) = (acc[i][j], acc[i][j+2])
                #pragma unroll
                for (int j = 0; j < 2; ++j) {
                    int d1 = tx + 16 * j;  // < 32
                    // inv_freq[d1] = 10000^(-d1/32)
                    float f = (float)sp * exp2f(-(float)d1 * (13.287712379549449f / 32.0f));
                    float sn, cs;
                    sincosf(f, &sn, &cs);
                    float lo = acc[i][j], hi = acc[i][j + 2];
                    C[base + d1]      = lo * cs - hi * sn;
                    C[base + d1 + 32] = hi * cs + lo * sn;
                }
            }
        }
    }
}

// ---------------- Attention: one block per (q-row, b*h) ----------------
__global__ __launch_bounds__(256) void attn_kernel(
    const float* __restrict__ Qt, const float* __restrict__ Kt,
    const float* __restrict__ Vt, const float* __restrict__ bias,
    const int* __restrict__ mask, float* __restrict__ attn,
    float* __restrict__ ho)
{
    __shared__ __align__(16) float qs[HD];
    __shared__ float sc[S_LEN];
    __shared__ float red[256];

    const int tid = threadIdx.x;
    const int q  = blockIdx.x;
    const int bh = blockIdx.y;
    const int b = bh >> 4, h = bh & 15;

    const float* qrow = Qt + ((size_t)bh * S_LEN + q) * HD;
    if (tid < HD) qs[tid] = qrow[tid];
    __syncthreads();

    // phase 1: scores for k in [0, q]
    float lmax = -3.0e38f;
    const int*   mrow = mask + b * S_LEN;
    const float* brow = bias + (size_t)q * S_LEN;
    for (int k = tid; k <= q; k += 256) {
        const float4* kr = (const float4*)(Kt + ((size_t)bh * S_LEN + k) * HD);
        const float4* q4 = (const float4*)qs;
        float dot = 0.f;
        #pragma unroll
        for (int d4 = 0; d4 < 16; ++d4) {
            float4 kv = kr[d4];
            float4 qv = q4[d4];
            dot += qv.x * kv.x + qv.y * kv.y + qv.z * kv.z + qv.w * kv.w;
        }
        float s = dot * 0.125f + brow[k];
        if (mrow[k] == 0) s = -3.0e38f;
        sc[k] = s;
        lmax = fmaxf(lmax, s);
    }
    red[tid] = lmax;
    __syncthreads();
    for (int st = 128; st > 0; st >>= 1) {
        if (tid < st) red[tid] = fmaxf(red[tid], red[tid + st]);
        __syncthreads();
    }
    float mx = red[0];
    __syncthreads();

    // phase 2: exp + sum
    float lsum = 0.f;
    for (int k = tid; k <= q; k += 256) {
        float p = __expf(sc[k] - mx);
        sc[k] = p;
        lsum += p;
    }
    red[tid] = lsum;
    __syncthreads();
    for (int st = 128; st > 0; st >>= 1) {
        if (tid < st) red[tid] += red[tid + st];
        __syncthreads();
    }
    float inv = 1.0f / red[0];
    __syncthreads();

    // phase 3: write attn row (zeros beyond causal boundary)
    float* arow = attn + ((size_t)bh * S_LEN + q) * S_LEN;
    for (int k = tid; k < S_LEN; k += 256)
        arow[k] = (k <= q) ? sc[k] * inv : 0.f;

    // phase 4: out[d] = sum_k p[k] * V[k][d]
    int g = tid >> 6, d = tid & 63;
    float acc = 0.f;
    for (int k = g; k <= q; k += 4)
        acc += sc[k] * Vt[((size_t)bh * S_LEN + k) * HD + d];
    red[tid] = acc;
    __syncthreads();
    if (tid < 64) {
        float o = (red[tid] + red[64 + tid] + red[128 + tid] + red[192 + tid]) * inv;
        ho[((size_t)(b * S_LEN + q)) * HID + h * HD + tid] = o;
    }
}

extern "C" void kernel_launch(void* const* d_in, const int* in_sizes, int n_in,
                              void* d_out, int out_size, void* d_ws, size_t ws_size,
                              hipStream_t stream) {
    const float* x     = (const float*)d_in[0];
    const int*   mask  = (const int*)d_in[1];
    const float* Wq    = (const float*)d_in[2];
    const float* Wk    = (const float*)d_in[3];
    const float* Wv    = (const float*)d_in[4];
    const float* Wo    = (const float*)d_in[5];
    const float* cbias = (const float*)d_in[6];

    float* out  = (float*)d_out;
    float* attn = out + (size_t)BATCH * S_LEN * HID;

    const size_t QKV_ELEMS = (size_t)BATCH * S_LEN * HID;  // 4,194,304
    float* ws = (float*)d_ws;
    float* Qt = ws;
    float* Kt = Qt + QKV_ELEMS;
    float* Vt = Kt + QKV_ELEMS;
    float* Ho = Vt + QKV_ELEMS;

    const int M = BATCH * S_LEN;  // 4096
    dim3 g(M / 64, HID / 64), blk(256);

    gemm_xwT<1><<<g, blk, 0, stream>>>(x, Wq, Qt, M, HID, HID);
    gemm_xwT<1><<<g, blk, 0, stream>>>(x, Wk, Kt, M, HID, HID);
    gemm_xwT<2><<<g, blk, 0, stream>>>(x, Wv, Vt, M, HID, HID);

    attn_kernel<<<dim3(S_LEN, BATCH * NH), blk, 0, stream>>>(
        Qt, Kt, Vt, cbias, mask, attn, Ho);

    gemm_xwT<0><<<g, blk, 0, stream>>>(Ho, Wo, out, M, HID, HID);
}

// Round 2
// 1816.848 us; speedup vs baseline: 2.4677x; 2.4677x over previous
//
#include <hip/hip_runtime.h>
#include <hip/hip_bf16.h>
#include <math.h>

#define S_LEN 2048
#define HID   1024
#define NH    16
#define HD    64
#define BATCH 2

typedef __bf16 bf16;
typedef __attribute__((ext_vector_type(8))) __bf16 bf16x8;
typedef __attribute__((ext_vector_type(4))) float f32x4;

// ---------------- GEMM: C = A @ W^T ----------------
// A: (M,K) row-major fp32, W: (N,K) row-major fp32.
// MODE 0: plain fp32 write C[m*N+n]                     (output projection)
// MODE 1: RoPE + transposed bf16 write to (B,NH,S,HD)   (Q, K)
// MODE 2: transposed bf16 write to (B,NH,S,HD)          (V)
template <int MODE, typename OutT>
__global__ __launch_bounds__(256) void gemm_xwT(
    const float* __restrict__ A, const float* __restrict__ W,
    OutT* __restrict__ C, int M, int N, int K)
{
    __shared__ float As[16][65];
    __shared__ float Bs[16][65];
    const int tid = threadIdx.x;
    const int tx = tid & 15, ty = tid >> 4;
    const int m0 = blockIdx.x * 64, n0 = blockIdx.y * 64;

    float acc[4][4] = {};

    for (int k0 = 0; k0 < K; k0 += 16) {
        #pragma unroll
        for (int l = 0; l < 4; ++l) {
            int e = tid + l * 256;
            int r = e >> 4, c = e & 15;
            As[c][r] = A[(size_t)(m0 + r) * K + k0 + c];
            Bs[c][r] = W[(size_t)(n0 + r) * K + k0 + c];
        }
        __syncthreads();
        #pragma unroll
        for (int kk = 0; kk < 16; ++kk) {
            float a[4], b[4];
            #pragma unroll
            for (int i = 0; i < 4; ++i) a[i] = As[kk][ty + 16 * i];
            #pragma unroll
            for (int j = 0; j < 4; ++j) b[j] = Bs[kk][tx + 16 * j];
            #pragma unroll
            for (int i = 0; i < 4; ++i)
                #pragma unroll
                for (int j = 0; j < 4; ++j)
                    acc[i][j] += a[i] * b[j];
        }
        __syncthreads();
    }

    if (MODE == 0) {
        #pragma unroll
        for (int i = 0; i < 4; ++i) {
            int m = m0 + ty + 16 * i;
            #pragma unroll
            for (int j = 0; j < 4; ++j) {
                int n = n0 + tx + 16 * j;
                C[(size_t)m * N + n] = (OutT)acc[i][j];
            }
        }
    } else {
        const int h = n0 >> 6;  // tile spans exactly one head
        #pragma unroll
        for (int i = 0; i < 4; ++i) {
            int m  = m0 + ty + 16 * i;
            int b  = m >> 11;          // / S_LEN
            int sp = m & (S_LEN - 1);  // % S_LEN
            size_t base = (((size_t)b * NH + h) * S_LEN + sp) * HD;
            if (MODE == 2) {
                #pragma unroll
                for (int j = 0; j < 4; ++j) {
                    int d = tx + 16 * j;
                    C[base + d] = (OutT)acc[i][j];
                }
            } else {  // MODE 1: RoPE. pair (d1, d1+32) = (acc[i][j], acc[i][j+2])
                #pragma unroll
                for (int j = 0; j < 2; ++j) {
                    int d1 = tx + 16 * j;  // < 32
                    float f = (float)sp * exp2f(-(float)d1 * (13.287712379549449f / 32.0f));
                    float sn, cs;
                    sincosf(f, &sn, &cs);
                    float lo = acc[i][j], hi = acc[i][j + 2];
                    C[base + d1]      = (OutT)(lo * cs - hi * sn);
                    C[base + d1 + 32] = (OutT)(hi * cs + lo * sn);
                }
            }
        }
    }
}

// ---------------- MFMA attention ----------------
// Block: 256 threads (4 waves). One block handles a 16-row q-tile for one bh.
// LDS: fp32 scores [16][2052] (+pad vs bank conflicts), ~132 KB total.
#define SC_PITCH 2052

__global__ __launch_bounds__(256) void attn_mfma(
    const bf16* __restrict__ Qt, const bf16* __restrict__ Kt,
    const bf16* __restrict__ Vt, const float* __restrict__ bias,
    const int* __restrict__ mask, float* __restrict__ attn,
    float* __restrict__ ho)
{
    extern __shared__ char smem[];
    float* sc     = (float*)smem;                 // [16][SC_PITCH]
    float* red    = sc + 16 * SC_PITCH;           // [256]
    float* rowmax = red + 256;                    // [16]
    float* invl   = rowmax + 16;                  // [16]

    const int tid  = threadIdx.x;
    const int lane = tid & 63;
    const int w    = tid >> 6;
    const int n    = lane & 15;      // MFMA "lane&15" index
    const int quad = lane >> 4;

    const int qt = 127 - blockIdx.x;       // reversed for load balance
    const int bh = blockIdx.y;
    const int b  = bh >> 4, h = bh & 15;
    const int q0 = qt * 16;
    const int ncols = q0 + 16;             // valid score region [0, ncols)
    const int T = qt + 1;                  // number of 16-wide k tiles

    // ---- Q fragments (same 16 q rows for all waves) ----
    const bf16* qbase = Qt + ((size_t)bh * S_LEN + q0 + n) * HD + quad * 8;
    bf16x8 qf0 = *(const bf16x8*)(qbase);
    bf16x8 qf1 = *(const bf16x8*)(qbase + 32);

    const int* mrow = mask + b * S_LEN;

    // ---- Phase 1: scores via MFMA, scatter to LDS with bias+mask ----
    for (int t = w; t < T; t += 4) {
        int k0 = t * 16;
        int krow = k0 + n;
        const bf16* kbase = Kt + ((size_t)bh * S_LEN + krow) * HD + quad * 8;
        bf16x8 b0 = *(const bf16x8*)(kbase);
        bf16x8 b1 = *(const bf16x8*)(kbase + 32);
        f32x4 c = {0.f, 0.f, 0.f, 0.f};
        c = __builtin_amdgcn_mfma_f32_16x16x32_bf16(qf0, b0, c, 0, 0, 0);
        c = __builtin_amdgcn_mfma_f32_16x16x32_bf16(qf1, b1, c, 0, 0, 0);
        int mk = mrow[krow];
        #pragma unroll
        for (int r = 0; r < 4; ++r) {
            int qr = quad * 4 + r;          // local q row (C layout)
            int qabs = q0 + qr;
            float s = c[r] * 0.125f + bias[(size_t)qabs * S_LEN + krow];
            if (krow > qabs || mk == 0) s = -3.0e38f;
            sc[qr * SC_PITCH + krow] = s;
        }
    }
    __syncthreads();

    // ---- Phase 2: row max ----
    {
        const int r = tid & 15, s_id = tid >> 4;
        float lmax = -3.0e38f;
        for (int c = s_id; c < ncols; c += 16)
            lmax = fmaxf(lmax, sc[r * SC_PITCH + c]);
        red[tid] = lmax;
        __syncthreads();
        #pragma unroll
        for (int st = 128; st >= 16; st >>= 1) {
            if (tid < st) red[tid] = fmaxf(red[tid], red[tid + st]);
            __syncthreads();
        }
        if (tid < 16) rowmax[tid] = red[tid];
        __syncthreads();

        // ---- Phase 3: exp in place + row sum ----
        float mx = rowmax[r];
        float lsum = 0.f;
        for (int c = s_id; c < ncols; c += 16) {
            float p = __expf(sc[r * SC_PITCH + c] - mx);
            sc[r * SC_PITCH + c] = p;
            lsum += p;
        }
        red[tid] = lsum;
        __syncthreads();
        #pragma unroll
        for (int st = 128; st >= 16; st >>= 1) {
            if (tid < st) red[tid] += red[tid + st];
            __syncthreads();
        }
        if (tid < 16) invl[tid] = 1.0f / red[tid];
        __syncthreads();
    }

    // ---- Phase 4: write normalized attn rows (zeros past ncols) ----
    for (int r2 = 0; r2 < 16; ++r2) {
        float iv = invl[r2];
        float* arow = attn + ((size_t)bh * S_LEN + q0 + r2) * S_LEN;
        for (int c = tid * 4; c < S_LEN; c += 1024) {
            float4 o;
            if (c < ncols) {
                const float* s4 = sc + r2 * SC_PITCH + c;
                o.x = s4[0] * iv; o.y = s4[1] * iv;
                o.z = s4[2] * iv; o.w = s4[3] * iv;
            } else {
                o.x = o.y = o.z = o.w = 0.f;
            }
            *(float4*)(arow + c) = o;
        }
    }

    // ---- Phase 5: PV via MFMA; wave w handles dims [w*16, w*16+16) ----
    {
        const int d = w * 16 + n;
        const int m = n;  // A-operand q row = lane&15
        f32x4 acc0 = {0.f, 0.f, 0.f, 0.f};
        f32x4 acc1 = {0.f, 0.f, 0.f, 0.f};
        int toggle = 0;
        for (int kc = 0; kc < ncols; kc += 32, toggle ^= 1) {
            bf16x8 af, vf;
            #pragma unroll
            for (int j = 0; j < 8; ++j) {
                int k = kc + quad * 8 + j;
                float pv = (k < ncols) ? sc[m * SC_PITCH + k] : 0.f;
                af[j] = (bf16)pv;
                vf[j] = Vt[((size_t)bh * S_LEN + k) * HD + d];  // k < S_LEN always
            }
            if (toggle == 0)
                acc0 = __builtin_amdgcn_mfma_f32_16x16x32_bf16(af, vf, acc0, 0, 0, 0);
            else
                acc1 = __builtin_amdgcn_mfma_f32_16x16x32_bf16(af, vf, acc1, 0, 0, 0);
        }
        #pragma unroll
        for (int r = 0; r < 4; ++r) {
            int qr = quad * 4 + r;
            float o = (acc0[r] + acc1[r]) * invl[qr];
            ho[((size_t)(b * S_LEN + q0 + qr)) * HID + h * HD + d] = o;
        }
    }
}

extern "C" void kernel_launch(void* const* d_in, const int* in_sizes, int n_in,
                              void* d_out, int out_size, void* d_ws, size_t ws_size,
                              hipStream_t stream) {
    const float* x     = (const float*)d_in[0];
    const int*   mask  = (const int*)d_in[1];
    const float* Wq    = (const float*)d_in[2];
    const float* Wk    = (const float*)d_in[3];
    const float* Wv    = (const float*)d_in[4];
    const float* Wo    = (const float*)d_in[5];
    const float* cbias = (const float*)d_in[6];

    float* out  = (float*)d_out;
    float* attn = out + (size_t)BATCH * S_LEN * HID;

    const size_t QKV_ELEMS = (size_t)BATCH * S_LEN * HID;  // 4,194,304
    char* ws = (char*)d_ws;
    bf16*  Qt = (bf16*)ws;
    bf16*  Kt = Qt + QKV_ELEMS;
    bf16*  Vt = Kt + QKV_ELEMS;
    float* Ho = (float*)(ws + 3 * QKV_ELEMS * sizeof(bf16));

    const int M = BATCH * S_LEN;  // 4096
    dim3 g(M / 64, HID / 64), blk(256);

    gemm_xwT<1, bf16><<<g, blk, 0, stream>>>(x, Wq, Qt, M, HID, HID);
    gemm_xwT<1, bf16><<<g, blk, 0, stream>>>(x, Wk, Kt, M, HID, HID);
    gemm_xwT<2, bf16><<<g, blk, 0, stream>>>(x, Wv, Vt, M, HID, HID);

    const size_t lds_bytes = (16 * SC_PITCH + 256 + 32) * sizeof(float);
    static bool attr_set = false;
    if (!attr_set) {
        hipFuncSetAttribute((const void*)attn_mfma,
                            hipFuncAttributeMaxDynamicSharedMemorySize,
                            (int)lds_bytes);
        attr_set = true;
    }
    attn_mfma<<<dim3(S_LEN / 16, BATCH * NH), blk, lds_bytes, stream>>>(
        Qt, Kt, Vt, cbias, mask, attn, Ho);

    gemm_xwT<0, float><<<g, blk, 0, stream>>>(Ho, Wo, out, M, HID, HID);
}